// Round 1
// baseline (859.283 us; speedup 1.0000x reference)
//
#include <hip/hip_runtime.h>

#define S_LEN 4096
#define B_SZ  32
#define DA    1024
#define DM    256
#define NCH   16      // s-chunks for the partial reduction
#define WINSZ 12
#define NEG_INF (-3.402823466e38f)

// ---------------------------------------------------------------------------
// K1: partial max/sum over s in [1, S) for x[b, s, d]; one block = 256 d's,
// one s-chunk, one batch. Coalesced: lanes map to consecutive d.
// Partial layout: p[ch * (B*D) + b*D + d]  (coalesced write AND read).
// ---------------------------------------------------------------------------
template <int D>
__global__ __launch_bounds__(256) void partial_reduce_kernel(
    const float* __restrict__ x, float* __restrict__ pmax, float* __restrict__ psum)
{
    const int d  = blockIdx.x * 256 + threadIdx.x;
    const int ch = blockIdx.y;
    const int b  = blockIdx.z;
    constexpr int total = S_LEN - 1;                 // 4095
    constexpr int per   = (total + NCH - 1) / NCH;   // 256
    const int s0 = 1 + ch * per;
    const int s1 = (s0 + per < S_LEN) ? (s0 + per) : S_LEN;

    const float* base = x + (size_t)b * S_LEN * D + d;
    float mx = NEG_INF;
    float sm = 0.0f;
#pragma unroll 4
    for (int s = s0; s < s1; ++s) {
        float v = base[(size_t)s * D];
        mx = fmaxf(mx, v);
        sm += v;
    }
    const size_t o = (size_t)ch * (B_SZ * D) + (size_t)b * D + d;
    pmax[o] = mx;
    psum[o] = sm;
}

// ---------------------------------------------------------------------------
// K2: fold NCH partials -> gmax[b*D+d], gsum[b*D+d]
// ---------------------------------------------------------------------------
template <int D>
__global__ __launch_bounds__(256) void final_reduce_kernel(
    const float* __restrict__ pmax, const float* __restrict__ psum,
    float* __restrict__ gmax, float* __restrict__ gsum)
{
    const int idx = blockIdx.x * 256 + threadIdx.x;  // b*D + d
    float mx = NEG_INF;
    float sm = 0.0f;
#pragma unroll
    for (int ch = 0; ch < NCH; ++ch) {
        mx = fmaxf(mx, pmax[(size_t)ch * (B_SZ * D) + idx]);
        sm += psum[(size_t)ch * (B_SZ * D) + idx];
    }
    gmax[idx] = mx;
    gsum[idx] = sm;
}

// ---------------------------------------------------------------------------
// Fused feature construction + dot product for one (x, D) tensor.
// Feature vector layout per row j (length 5*D):
//   seg0: x[b, gap[j], d]                              (gather)
//   row 0:  seg1 gmax, seg2 gsum/denom0, seg3 g2max, seg4 g2avg
//   row>=1: seg1 winmax(offs1), seg2 winavg(offs1),
//           seg3 winmax(offs2), seg4 winavg(offs2)
// Returns per-thread partial dot with w.
// ---------------------------------------------------------------------------
__device__ float feat_dot(const float* __restrict__ x, int D, int b, int row,
                          const int* gaps, const float* __restrict__ mask,
                          const float* __restrict__ gmax, const float* __restrict__ gsum,
                          float denom0, const float* __restrict__ w, int tid)
{
    const int gr = gaps[row];
    const size_t bbase = (size_t)b * S_LEN * D;
    const float* mrow = mask + (size_t)b * S_LEN;
    float acc = 0.0f;

    for (int k = tid; k < 5 * D; k += 256) {
        const int seg = k / D;
        const int d   = k - seg * D;
        float feat;
        if (seg == 0) {
            feat = x[bbase + (size_t)gr * D + d];
        } else if (row == 0) {
            if (seg == 1) {
                feat = gmax[b * D + d];
            } else if (seg == 2) {
                feat = gsum[b * D + d] / denom0;
            } else {
                // gap pools over rows 1..4
                float mx = NEG_INF, sm = 0.0f;
#pragma unroll
                for (int r = 1; r < 5; ++r) {
                    float v = x[bbase + (size_t)gaps[r] * D + d];
                    mx = fmaxf(mx, v);
                    sm += v;
                }
                feat = (seg == 3) ? mx : sm * 0.25f;
            }
        } else {
            // window pools around gap[row]; seg1/2 -> offsets -12..-1, seg3/4 -> 1..12
            const int o0 = (seg <= 2) ? -WINSZ : 1;
            float mx = 0.0f;   // reference clamps max at 0
            float sm = 0.0f;
            float wsum = 0.0f;
#pragma unroll
            for (int t = 0; t < WINSZ; ++t) {
                const int pos = gr + o0 + t;
                if (pos >= 0 && pos < S_LEN) {
                    const float wm = mrow[pos];
                    const float v  = x[bbase + (size_t)pos * D + d] * wm;
                    mx = fmaxf(mx, v);
                    sm += v;
                    wsum += wm;
                }
            }
            feat = ((seg & 1) != 0) ? mx : sm / wsum;   // seg1,3 = max; seg2,4 = avg
        }
        acc += feat * w[k];
    }
    return acc;
}

// ---------------------------------------------------------------------------
// K3: one block per (b, row). Computes denom0, gathers gaps, builds features
// on the fly fused with the dot products, writes logits[b*5+row].
// ---------------------------------------------------------------------------
__global__ __launch_bounds__(256) void logits_kernel(
    const float* __restrict__ att, const float* __restrict__ mod,
    const int* __restrict__ gap_indices, const float* __restrict__ mask,
    const float* __restrict__ w_att, const float* __restrict__ b_att,
    const float* __restrict__ w_mod, const float* __restrict__ b_mod,
    const float* __restrict__ w_att_s, const float* __restrict__ b_att_s,
    const float* __restrict__ w_mod_s, const float* __restrict__ b_mod_s,
    const float* __restrict__ gmax_att, const float* __restrict__ gsum_att,
    const float* __restrict__ gmax_mod, const float* __restrict__ gsum_mod,
    float* __restrict__ out)
{
    const int b   = blockIdx.x / 5;
    const int row = blockIdx.x % 5;
    const int tid = threadIdx.x;

    __shared__ float red[256];

    // denom0 = sum(mask[b, :]) - 1
    float ms = 0.0f;
    for (int s = tid; s < S_LEN; s += 256) ms += mask[(size_t)b * S_LEN + s];
    red[tid] = ms;
    __syncthreads();
#pragma unroll
    for (int wd = 128; wd > 0; wd >>= 1) {
        if (tid < wd) red[tid] += red[tid + wd];
        __syncthreads();
    }
    const float denom0 = red[0] - 1.0f;
    __syncthreads();

    int gaps[5];
#pragma unroll
    for (int i = 0; i < 5; ++i) gaps[i] = gap_indices[b * 5 + i];

    const float* wa = (row == 0) ? w_att_s : w_att;
    const float* wm = (row == 0) ? w_mod_s : w_mod;

    float acc = feat_dot(att, DA, b, row, gaps, mask, gmax_att, gsum_att, denom0, wa, tid)
              + feat_dot(mod, DM, b, row, gaps, mask, gmax_mod, gsum_mod, denom0, wm, tid);

    red[tid] = acc;
    __syncthreads();
#pragma unroll
    for (int wd = 128; wd > 0; wd >>= 1) {
        if (tid < wd) red[tid] += red[tid + wd];
        __syncthreads();
    }
    if (tid == 0) {
        const float bias = (row == 0) ? (b_att_s[0] + b_mod_s[0]) : (b_att[0] + b_mod[0]);
        out[b * 5 + row] = red[0] + bias;
    }
}

// ---------------------------------------------------------------------------
extern "C" void kernel_launch(void* const* d_in, const int* in_sizes, int n_in,
                              void* d_out, int out_size, void* d_ws, size_t ws_size,
                              hipStream_t stream)
{
    const float* att    = (const float*)d_in[0];
    const float* mod    = (const float*)d_in[1];
    const int*   gap    = (const int*)d_in[2];
    const float* mask   = (const float*)d_in[3];
    const float* w_att  = (const float*)d_in[4];
    const float* b_att  = (const float*)d_in[5];
    const float* w_mod  = (const float*)d_in[6];
    const float* b_mod  = (const float*)d_in[7];
    const float* w_att_s = (const float*)d_in[8];
    const float* b_att_s = (const float*)d_in[9];
    const float* w_mod_s = (const float*)d_in[10];
    const float* b_mod_s = (const float*)d_in[11];
    float* out = (float*)d_out;

    // workspace layout (floats)
    float* ws = (float*)d_ws;
    float* pmax_att = ws;                       // NCH*B*DA = 524288
    float* psum_att = pmax_att + (size_t)NCH * B_SZ * DA;
    float* pmax_mod = psum_att + (size_t)NCH * B_SZ * DA;   // NCH*B*DM = 131072
    float* psum_mod = pmax_mod + (size_t)NCH * B_SZ * DM;
    float* gmax_att = psum_mod + (size_t)NCH * B_SZ * DM;   // B*DA
    float* gsum_att = gmax_att + (size_t)B_SZ * DA;
    float* gmax_mod = gsum_att + (size_t)B_SZ * DA;         // B*DM
    float* gsum_mod = gmax_mod + (size_t)B_SZ * DM;

    partial_reduce_kernel<DA><<<dim3(DA / 256, NCH, B_SZ), 256, 0, stream>>>(att, pmax_att, psum_att);
    partial_reduce_kernel<DM><<<dim3(DM / 256, NCH, B_SZ), 256, 0, stream>>>(mod, pmax_mod, psum_mod);

    final_reduce_kernel<DA><<<(B_SZ * DA) / 256, 256, 0, stream>>>(pmax_att, psum_att, gmax_att, gsum_att);
    final_reduce_kernel<DM><<<(B_SZ * DM) / 256, 256, 0, stream>>>(pmax_mod, psum_mod, gmax_mod, gsum_mod);

    logits_kernel<<<B_SZ * 5, 256, 0, stream>>>(
        att, mod, gap, mask,
        w_att, b_att, w_mod, b_mod,
        w_att_s, b_att_s, w_mod_s, b_mod_s,
        gmax_att, gsum_att, gmax_mod, gsum_mod, out);
}

// Round 2
// 815.923 us; speedup vs baseline: 1.0531x; 1.0531x over previous
//
#include <hip/hip_runtime.h>

#define S_LEN 4096
#define B_SZ  32
#define DA    1024
#define DM    256
#define NCHA  64      // att s-chunks (64 rows each)
#define NCHM  32      // mod s-chunks (128 rows each)
#define NSPLIT 4      // k-range splits for the logits kernel
#define WINSZ 12
#define NEG_INF (-3.402823466e38f)

// ---------------------------------------------------------------------------
// K1a: att partial max/sum over s in [1,S). One block = (chunk, b); threads
// cover one full 4 KB row via float4 (tid*4), s walks sequentially ->
// contiguous streaming, 1 KiB per wave instruction.
// Partial layout: p[(ch*B + b)*DA + d], float4-coalesced writes.
// ---------------------------------------------------------------------------
__global__ __launch_bounds__(256) void reduce_att_kernel(
    const float* __restrict__ x, float* __restrict__ pmax, float* __restrict__ psum)
{
    const int ch = blockIdx.x, b = blockIdx.y, tid = threadIdx.x;
    const int s0 = 1 + ch * 64;
    const int s1 = (s0 + 64 < S_LEN) ? (s0 + 64) : S_LEN;
    const float* base = x + (size_t)b * S_LEN * DA + tid * 4;

    float4 mx = make_float4(NEG_INF, NEG_INF, NEG_INF, NEG_INF);
    float4 sm = make_float4(0.f, 0.f, 0.f, 0.f);
#pragma unroll 4
    for (int s = s0; s < s1; ++s) {
        const float4 v = *(const float4*)(base + (size_t)s * DA);
        mx.x = fmaxf(mx.x, v.x); sm.x += v.x;
        mx.y = fmaxf(mx.y, v.y); sm.y += v.y;
        mx.z = fmaxf(mx.z, v.z); sm.z += v.z;
        mx.w = fmaxf(mx.w, v.w); sm.w += v.w;
    }
    const size_t o = ((size_t)ch * B_SZ + b) * DA + (size_t)tid * 4;
    *(float4*)(pmax + o) = mx;
    *(float4*)(psum + o) = sm;
}

// ---------------------------------------------------------------------------
// K1b: mod partial max/sum. Row = 1 KB = 64 float4; 256 threads cover 4
// consecutive rows per iteration (group g = tid>>6 handles row s0+4i+g).
// LDS-fold the 4 groups at the end.
// ---------------------------------------------------------------------------
__global__ __launch_bounds__(256) void reduce_mod_kernel(
    const float* __restrict__ x, float* __restrict__ pmax, float* __restrict__ psum)
{
    const int ch = blockIdx.x, b = blockIdx.y;
    const int g = threadIdx.x >> 6, l = threadIdx.x & 63;
    const int s0 = 1 + ch * 128;
    const int s1 = (s0 + 128 < S_LEN) ? (s0 + 128) : S_LEN;
    const float* base = x + (size_t)b * S_LEN * DM + l * 4;

    float4 mx = make_float4(NEG_INF, NEG_INF, NEG_INF, NEG_INF);
    float4 sm = make_float4(0.f, 0.f, 0.f, 0.f);
    for (int s = s0 + g; s < s1; s += 4) {
        const float4 v = *(const float4*)(base + (size_t)s * DM);
        mx.x = fmaxf(mx.x, v.x); sm.x += v.x;
        mx.y = fmaxf(mx.y, v.y); sm.y += v.y;
        mx.z = fmaxf(mx.z, v.z); sm.z += v.z;
        mx.w = fmaxf(mx.w, v.w); sm.w += v.w;
    }
    __shared__ float4 smx[256], ssm[256];
    smx[threadIdx.x] = mx; ssm[threadIdx.x] = sm;
    __syncthreads();
    if (threadIdx.x < 64) {
#pragma unroll
        for (int gg = 1; gg < 4; ++gg) {
            const float4 omx = smx[gg * 64 + l], osm = ssm[gg * 64 + l];
            mx.x = fmaxf(mx.x, omx.x); sm.x += osm.x;
            mx.y = fmaxf(mx.y, omx.y); sm.y += osm.y;
            mx.z = fmaxf(mx.z, omx.z); sm.z += osm.z;
            mx.w = fmaxf(mx.w, omx.w); sm.w += osm.w;
        }
        const size_t o = ((size_t)ch * B_SZ + b) * DM + (size_t)l * 4;
        *(float4*)(pmax + o) = mx;
        *(float4*)(psum + o) = sm;
    }
}

// ---------------------------------------------------------------------------
// K2: fold NCH chunk partials -> gmax/gsum. float4 per thread.
// grid = TOT/1024 blocks, TOT = B*D.
// ---------------------------------------------------------------------------
template <int NCH_, int TOT>
__global__ __launch_bounds__(256) void fold_kernel(
    const float* __restrict__ pmax, const float* __restrict__ psum,
    float* __restrict__ gmax, float* __restrict__ gsum)
{
    const size_t base = ((size_t)blockIdx.x * 256 + threadIdx.x) * 4;
    float4 mx = make_float4(NEG_INF, NEG_INF, NEG_INF, NEG_INF);
    float4 sm = make_float4(0.f, 0.f, 0.f, 0.f);
#pragma unroll
    for (int ch = 0; ch < NCH_; ++ch) {
        const float4 m = *(const float4*)(pmax + (size_t)ch * TOT + base);
        const float4 s = *(const float4*)(psum + (size_t)ch * TOT + base);
        mx.x = fmaxf(mx.x, m.x); sm.x += s.x;
        mx.y = fmaxf(mx.y, m.y); sm.y += s.y;
        mx.z = fmaxf(mx.z, m.z); sm.z += s.z;
        mx.w = fmaxf(mx.w, m.w); sm.w += s.w;
    }
    *(float4*)(gmax + base) = mx;
    *(float4*)(gsum + base) = sm;
}

// ---------------------------------------------------------------------------
// K0: denom0[b] = sum(mask[b,:]) - 1
// ---------------------------------------------------------------------------
__global__ __launch_bounds__(256) void denom_kernel(
    const float* __restrict__ mask, float* __restrict__ denom)
{
    const int b = blockIdx.x, tid = threadIdx.x;
    const float4 v = *(const float4*)(mask + (size_t)b * S_LEN + tid * 4);
    float s = v.x + v.y + v.z + v.w;
    __shared__ float red[256];
    red[tid] = s;
    __syncthreads();
#pragma unroll
    for (int wd = 128; wd > 0; wd >>= 1) {
        if (tid < wd) red[tid] += red[tid + wd];
        __syncthreads();
    }
    if (tid == 0) denom[b] = red[0] - 1.0f;
}

// ---------------------------------------------------------------------------
// Fused feature construction + dot partial for one (x, D) tensor.
// k strided by 256*NSPLIT starting at split*256 + tid.
// ---------------------------------------------------------------------------
__device__ float feat_dot(const float* __restrict__ x, int D, int b, int row,
                          const int* gaps, const float* __restrict__ mask,
                          const float* __restrict__ gmax, const float* __restrict__ gsum,
                          float denom0, const float* __restrict__ w, int k0)
{
    const int gr = gaps[row];
    const size_t bbase = (size_t)b * S_LEN * D;
    const float* mrow = mask + (size_t)b * S_LEN;
    float acc = 0.0f;

    for (int k = k0; k < 5 * D; k += 256 * NSPLIT) {
        const int seg = k / D;
        const int d   = k - seg * D;
        float feat;
        if (seg == 0) {
            feat = x[bbase + (size_t)gr * D + d];
        } else if (row == 0) {
            if (seg == 1) {
                feat = gmax[b * D + d];
            } else if (seg == 2) {
                feat = gsum[b * D + d] / denom0;
            } else {
                float mx = NEG_INF, sm = 0.0f;
#pragma unroll
                for (int r = 1; r < 5; ++r) {
                    const float v = x[bbase + (size_t)gaps[r] * D + d];
                    mx = fmaxf(mx, v);
                    sm += v;
                }
                feat = (seg == 3) ? mx : sm * 0.25f;
            }
        } else {
            const int o0 = (seg <= 2) ? -WINSZ : 1;
            float mx = 0.0f;   // reference clamps window max at 0
            float sm = 0.0f;
            float wsum = 0.0f;
#pragma unroll
            for (int t = 0; t < WINSZ; ++t) {
                const int pos = gr + o0 + t;
                if (pos >= 0 && pos < S_LEN) {
                    const float wm = mrow[pos];
                    const float v  = x[bbase + (size_t)pos * D + d] * wm;
                    mx = fmaxf(mx, v);
                    sm += v;
                    wsum += wm;
                }
            }
            feat = ((seg & 1) != 0) ? mx : sm / wsum;  // odd seg = max, even = avg
        }
        acc += feat * w[k];
    }
    return acc;
}

// ---------------------------------------------------------------------------
// K3: grid (NSPLIT, 5, B). Each block computes a partial dot over its
// k-slice for att+mod, writes part[(b*5+row)*NSPLIT + split].
// ---------------------------------------------------------------------------
__global__ __launch_bounds__(256) void logits_partial_kernel(
    const float* __restrict__ att, const float* __restrict__ mod,
    const int* __restrict__ gap_indices, const float* __restrict__ mask,
    const float* __restrict__ w_att, const float* __restrict__ w_mod,
    const float* __restrict__ w_att_s, const float* __restrict__ w_mod_s,
    const float* __restrict__ gmax_att, const float* __restrict__ gsum_att,
    const float* __restrict__ gmax_mod, const float* __restrict__ gsum_mod,
    const float* __restrict__ denom, float* __restrict__ part)
{
    const int split = blockIdx.x;
    const int row   = blockIdx.y;
    const int b     = blockIdx.z;
    const int tid   = threadIdx.x;
    const int k0    = split * 256 + tid;

    int gaps[5];
#pragma unroll
    for (int i = 0; i < 5; ++i) gaps[i] = gap_indices[b * 5 + i];
    const float denom0 = denom[b];

    const float* wa = (row == 0) ? w_att_s : w_att;
    const float* wm = (row == 0) ? w_mod_s : w_mod;

    float acc = feat_dot(att, DA, b, row, gaps, mask, gmax_att, gsum_att, denom0, wa, k0)
              + feat_dot(mod, DM, b, row, gaps, mask, gmax_mod, gsum_mod, denom0, wm, k0);

    __shared__ float red[256];
    red[tid] = acc;
    __syncthreads();
#pragma unroll
    for (int wd = 128; wd > 0; wd >>= 1) {
        if (tid < wd) red[tid] += red[tid + wd];
        __syncthreads();
    }
    if (tid == 0) part[((size_t)b * 5 + row) * NSPLIT + split] = red[0];
}

// ---------------------------------------------------------------------------
// K4: out[i] = sum_{split} part[i*NSPLIT+split] + bias(row)
// ---------------------------------------------------------------------------
__global__ __launch_bounds__(256) void logits_final_kernel(
    const float* __restrict__ part,
    const float* __restrict__ b_att, const float* __restrict__ b_mod,
    const float* __restrict__ b_att_s, const float* __restrict__ b_mod_s,
    float* __restrict__ out)
{
    const int i = threadIdx.x;
    if (i < B_SZ * 5) {
        float s = 0.0f;
#pragma unroll
        for (int sp = 0; sp < NSPLIT; ++sp) s += part[(size_t)i * NSPLIT + sp];
        const int row = i % 5;
        const float bias = (row == 0) ? (b_att_s[0] + b_mod_s[0]) : (b_att[0] + b_mod[0]);
        out[i] = s + bias;
    }
}

// ---------------------------------------------------------------------------
extern "C" void kernel_launch(void* const* d_in, const int* in_sizes, int n_in,
                              void* d_out, int out_size, void* d_ws, size_t ws_size,
                              hipStream_t stream)
{
    const float* att     = (const float*)d_in[0];
    const float* mod     = (const float*)d_in[1];
    const int*   gap     = (const int*)d_in[2];
    const float* mask    = (const float*)d_in[3];
    const float* w_att   = (const float*)d_in[4];
    const float* b_att   = (const float*)d_in[5];
    const float* w_mod   = (const float*)d_in[6];
    const float* b_mod   = (const float*)d_in[7];
    const float* w_att_s = (const float*)d_in[8];
    const float* b_att_s = (const float*)d_in[9];
    const float* w_mod_s = (const float*)d_in[10];
    const float* b_mod_s = (const float*)d_in[11];
    float* out = (float*)d_out;

    // workspace layout (floats)
    float* ws = (float*)d_ws;
    float* pmax_att = ws;                                        // NCHA*B*DA
    float* psum_att = pmax_att + (size_t)NCHA * B_SZ * DA;
    float* pmax_mod = psum_att + (size_t)NCHA * B_SZ * DA;       // NCHM*B*DM
    float* psum_mod = pmax_mod + (size_t)NCHM * B_SZ * DM;
    float* gmax_att = psum_mod + (size_t)NCHM * B_SZ * DM;       // B*DA
    float* gsum_att = gmax_att + (size_t)B_SZ * DA;
    float* gmax_mod = gsum_att + (size_t)B_SZ * DA;              // B*DM
    float* gsum_mod = gmax_mod + (size_t)B_SZ * DM;
    float* denom    = gsum_mod + (size_t)B_SZ * DM;              // B
    float* part     = denom + B_SZ;                              // B*5*NSPLIT

    denom_kernel<<<B_SZ, 256, 0, stream>>>(mask, denom);

    reduce_att_kernel<<<dim3(NCHA, B_SZ), 256, 0, stream>>>(att, pmax_att, psum_att);
    reduce_mod_kernel<<<dim3(NCHM, B_SZ), 256, 0, stream>>>(mod, pmax_mod, psum_mod);

    fold_kernel<NCHA, B_SZ * DA><<<(B_SZ * DA) / 1024, 256, 0, stream>>>(
        pmax_att, psum_att, gmax_att, gsum_att);
    fold_kernel<NCHM, B_SZ * DM><<<(B_SZ * DM) / 1024, 256, 0, stream>>>(
        pmax_mod, psum_mod, gmax_mod, gsum_mod);

    logits_partial_kernel<<<dim3(NSPLIT, 5, B_SZ), 256, 0, stream>>>(
        att, mod, gap, mask,
        w_att, w_mod, w_att_s, w_mod_s,
        gmax_att, gsum_att, gmax_mod, gsum_mod, denom, part);

    logits_final_kernel<<<1, 256, 0, stream>>>(part, b_att, b_mod, b_att_s, b_mod_s, out);
}